// Round 3
// baseline (668.314 us; speedup 1.0000x reference)
//
#include <hip/hip_runtime.h>
#include <cstdint>
#include <cstddef>

#define D_DIM 20000
#define C4    5000           // D_DIM / 4 float4 chunks per row
#define K_SEL 1000
#define BLK   256
#define JPT   20             // float4 chunks per thread: BLK*JPT = 5120 >= C4
#define NW    (BLK / 64)     // 4 waves per block
#define CAP   1024           // candidate buffer for exact bracket select

// Bracket for the k=1000 / n=20000 order statistic of N(0,1):
// mean 1.6449, sd 0.01495 -> +/- 8 sigma. Pure performance heuristic:
// rows outside the bracket take the exact bitwise-search fallback below,
// so correctness holds for ANY input.
#define T_LO_F 1.5253f
#define T_HI_F 1.7645f

typedef float vf4 __attribute__((ext_vector_type(4)));   // native vector: OK for nontemporal builtin

// monotonic float -> uint key (larger float => larger key)
__device__ __forceinline__ uint32_t f2k(float f) {
    uint32_t b = __float_as_uint(f);
    return (b & 0x80000000u) ? ~b : (b | 0x80000000u);
}
__device__ __forceinline__ float k2f(uint32_t k) {
    uint32_t b = (k & 0x80000000u) ? (k & 0x7FFFFFFFu) : ~k;
    return __uint_as_float(b);
}

__device__ __forceinline__ uint32_t wave_sum(uint32_t v) {
    #pragma unroll
    for (int d = 32; d >= 1; d >>= 1) v += __shfl_xor(v, d, 64);
    return v;
}

__global__ void __launch_bounds__(BLK, 8)   // 8 waves/EU -> 8 blocks/CU, 64-VGPR cap
wta_kernel(const float* __restrict__ in, float* __restrict__ out) {
    const int row  = blockIdx.x;
    const int tid  = threadIdx.x;
    const int lane = tid & 63;
    const int wid  = tid >> 6;

    __shared__ uint32_t cand[CAP];           // 4 KB
    __shared__ uint32_t ccnt;                // candidates collected
    __shared__ uint32_t s_hi;                // count of keys > KHI
    __shared__ uint32_t s_t0;                // fallback reduce slots
    __shared__ uint32_t s_t1;
    __shared__ uint32_t bc[3];               // 0: T, 1: budget, 2: m (count == T)
    __shared__ uint32_t waveTot[NW];

    const float4* in4  = (const float4*)(in  + (size_t)row * D_DIM);
    vf4*          out4 = (vf4*)         (out + (size_t)row * D_DIM);

    if (tid == 0) { ccnt = 0u; s_hi = 0u; }
    __syncthreads();

    const uint32_t KHI = f2k(T_HI_F);
    const uint32_t KLO = f2k(T_LO_F);

    // ---- pass A: stream row, count > KHI, collect bracket candidates ----
    uint32_t cnt_hi = 0;
    #pragma unroll
    for (int j = 0; j < JPT; ++j) {
        int c = j * BLK + tid;
        if (c < C4) {
            float4 v = in4[c];
            uint32_t k0 = f2k(v.x), k1 = f2k(v.y), k2 = f2k(v.z), k3 = f2k(v.w);
            cnt_hi += (k0 > KHI) ? 1u : 0u;
            cnt_hi += (k1 > KHI) ? 1u : 0u;
            cnt_hi += (k2 > KHI) ? 1u : 0u;
            cnt_hi += (k3 > KHI) ? 1u : 0u;
            if (k0 > KLO && k0 <= KHI) { uint32_t p = atomicAdd(&ccnt, 1u); if (p < CAP) cand[p] = k0; }
            if (k1 > KLO && k1 <= KHI) { uint32_t p = atomicAdd(&ccnt, 1u); if (p < CAP) cand[p] = k1; }
            if (k2 > KLO && k2 <= KHI) { uint32_t p = atomicAdd(&ccnt, 1u); if (p < CAP) cand[p] = k2; }
            if (k3 > KLO && k3 <= KHI) { uint32_t p = atomicAdd(&ccnt, 1u); if (p < CAP) cand[p] = k3; }
        }
    }
    uint32_t wsum = wave_sum(cnt_hi);
    if (lane == 0) atomicAdd(&s_hi, wsum);
    __syncthreads();

    const uint32_t hi = s_hi;
    const uint32_t cm = ccnt;

    if (hi < K_SEL && K_SEL <= hi + cm && cm <= CAP) {
        // ---- exact select among the bracket candidates (expected ~490) ----
        const uint32_t kp = K_SEL - hi;      // rank of target within cand
        for (uint32_t idx = (uint32_t)tid; idx < cm; idx += BLK) {
            uint32_t x = cand[idx];
            uint32_t gt = 0, eq = 0;
            uint32_t j = 0;
            for (; j + 8 <= cm; j += 8) {    // unrolled: 8 LDS broadcast reads in flight
                #pragma unroll
                for (int u = 0; u < 8; ++u) {
                    uint32_t y = cand[j + u];
                    gt += (y > x) ? 1u : 0u;
                    eq += (y == x) ? 1u : 0u;
                }
            }
            for (; j < cm; ++j) {
                uint32_t y = cand[j];
                gt += (y > x) ? 1u : 0u;
                eq += (y == x) ? 1u : 0u;
            }
            if (gt < kp && kp <= gt + eq) {    // unique value-class wins
                bc[0] = x;                     // T (kth-largest key)
                bc[1] = kp - gt;               // budget among == T
                bc[2] = eq;                    // m
            }
        }
        __syncthreads();
    } else {
        // ---- exact fallback for any input: bitwise threshold search,
        // streaming the row from cache each probe (correctness-only path,
        // never taken for in-bracket rows).
        uint32_t prefix = 0;
        for (int b = 31; b >= 0; --b) {
            uint32_t probe = prefix | (1u << b);
            uint32_t cth = 0;
            #pragma unroll
            for (int j = 0; j < JPT; ++j) {
                int c = j * BLK + tid;
                if (c < C4) {
                    float4 v = in4[c];
                    cth += (f2k(v.x) >= probe) ? 1u : 0u;
                    cth += (f2k(v.y) >= probe) ? 1u : 0u;
                    cth += (f2k(v.z) >= probe) ? 1u : 0u;
                    cth += (f2k(v.w) >= probe) ? 1u : 0u;
                }
            }
            uint32_t t = wave_sum(cth);
            if (tid == 0) s_t0 = 0u;
            __syncthreads();
            if (lane == 0) atomicAdd(&s_t0, t);
            __syncthreads();
            uint32_t total = s_t0;
            __syncthreads();
            if (total >= K_SEL) prefix = probe;
        }
        uint32_t g = 0, q = 0;
        #pragma unroll
        for (int j = 0; j < JPT; ++j) {
            int c = j * BLK + tid;
            if (c < C4) {
                float4 v = in4[c];
                uint32_t kk[4] = { f2k(v.x), f2k(v.y), f2k(v.z), f2k(v.w) };
                #pragma unroll
                for (int u = 0; u < 4; ++u) {
                    g += (kk[u] >  prefix) ? 1u : 0u;
                    q += (kk[u] == prefix) ? 1u : 0u;
                }
            }
        }
        uint32_t tg = wave_sum(g);
        uint32_t tq = wave_sum(q);
        if (tid == 0) { s_t0 = 0u; s_t1 = 0u; }
        __syncthreads();
        if (lane == 0) { atomicAdd(&s_t0, tg); atomicAdd(&s_t1, tq); }
        __syncthreads();
        if (tid == 0) { bc[0] = prefix; bc[1] = K_SEL - s_t0; bc[2] = s_t1; }
        __syncthreads();
    }

    const uint32_t T      = bc[0];             // exact K-th largest key
    const uint32_t budget = bc[1];             // how many keys == T to keep
    const uint32_t m      = bc[2];             // how many keys == T exist

    if (m == budget) {
        // ---- pass B (fast path): keep everything >= T; re-read hits L2/L3 ----
        #pragma unroll
        for (int j = 0; j < JPT; ++j) {
            int c = j * BLK + tid;
            if (c < C4) {
                float4 v = in4[c];
                uint32_t k0 = f2k(v.x), k1 = f2k(v.y), k2 = f2k(v.z), k3 = f2k(v.w);
                vf4 o;
                o.x = (k0 >= T) ? v.x : 0.0f;
                o.y = (k1 >= T) ? v.y : 0.0f;
                o.z = (k2 >= T) ? v.z : 0.0f;
                o.w = (k3 >= T) ? v.w : 0.0f;
                __builtin_nontemporal_store(o, &out4[c]);
            }
        }
    } else {
        // ---- rare tie path: among keys == T keep only the `budget` smallest
        // column indices (matches jax.lax.top_k stable tie-break). Chunk order
        // == (j, tid) order == increasing column order, so an ordered block
        // scan gives exact ranks.
        uint32_t running = 0;
        #pragma unroll
        for (int j = 0; j < JPT; ++j) {
            int c = j * BLK + tid;
            bool valid = (c < C4);
            float4 v;
            uint32_t k0 = 0u, k1 = 0u, k2 = 0u, k3 = 0u;
            if (valid) {
                v = in4[c];
                k0 = f2k(v.x); k1 = f2k(v.y); k2 = f2k(v.z); k3 = f2k(v.w);
            }
            uint32_t f0 = (valid && k0 == T) ? 1u : 0u;
            uint32_t f1 = (valid && k1 == T) ? 1u : 0u;
            uint32_t f2 = (valid && k2 == T) ? 1u : 0u;
            uint32_t f3 = (valid && k3 == T) ? 1u : 0u;
            uint32_t cnt = f0 + f1 + f2 + f3;

            uint32_t inc = cnt;
            #pragma unroll
            for (int d = 1; d < 64; d <<= 1) {
                uint32_t w = __shfl_up(inc, d, 64);
                if (lane >= d) inc += w;
            }
            if (lane == 63) waveTot[wid] = inc;
            __syncthreads();
            uint32_t waveBefore = 0, blockTot = 0;
            #pragma unroll
            for (int w = 0; w < NW; ++w) {
                uint32_t t = waveTot[w];
                blockTot += t;
                if (w < wid) waveBefore += t;
            }
            uint32_t base = running + waveBefore + (inc - cnt);
            uint32_t r0 = base;
            uint32_t r1 = base + f0;
            uint32_t r2 = base + f0 + f1;
            uint32_t r3 = base + f0 + f1 + f2;
            if (valid) {
                float4 o;
                o.x = (k0 > T || (f0 && r0 < budget)) ? v.x : 0.0f;
                o.y = (k1 > T || (f1 && r1 < budget)) ? v.y : 0.0f;
                o.z = (k2 > T || (f2 && r2 < budget)) ? v.z : 0.0f;
                o.w = (k3 > T || (f3 && r3 < budget)) ? v.w : 0.0f;
                ((float4*)out4)[c] = o;
            }
            running += blockTot;
            __syncthreads();                   // waveTot reuse next j
        }
    }
}

extern "C" void kernel_launch(void* const* d_in, const int* in_sizes, int n_in,
                              void* d_out, int out_size, void* d_ws, size_t ws_size,
                              hipStream_t stream) {
    const float* in  = (const float*)d_in[0];
    float*       out = (float*)d_out;
    const int B = in_sizes[0] / D_DIM;         // 4096 rows
    wta_kernel<<<dim3(B), dim3(BLK), 0, stream>>>(in, out);
}

// Round 4
// 622.486 us; speedup vs baseline: 1.0736x; 1.0736x over previous
//
#include <hip/hip_runtime.h>
#include <cstdint>
#include <cstddef>

#define D_DIM 20000
#define C4    5000           // D_DIM / 4 float4 chunks per row
#define K_SEL 1000
#define BLK   1024
#define JPT   5              // float4 chunks per thread: BLK*JPT = 5120 >= C4
#define NW    (BLK / 64)     // 16 waves per block
#define CAP   896            // candidate buffer for exact bracket select
#define ROWS  16             // rows per block -> grid = 4096/16 = 256 (1 block/CU)

// Bracket for the k=1000 / n=20000 order statistic of N(0,1):
// mean 1.6449, sd 0.01494 -> +/- 6 sigma. Pure performance heuristic:
// rows outside the bracket take the exact bitwise-search fallback below,
// so correctness holds for ANY input.
#define T_LO_F 1.5552f
#define T_HI_F 1.7346f

typedef float vf4 __attribute__((ext_vector_type(4)));

// monotonic float-bits -> uint key (larger float => larger key); involution pair
__device__ __forceinline__ uint32_t f2k(uint32_t b) {
    return b ^ (uint32_t)(((int32_t)b >> 31) | (int32_t)0x80000000);
}

__device__ __forceinline__ uint32_t wave_sum(uint32_t v) {
    #pragma unroll
    for (int d = 32; d >= 1; d >>= 1) v += __shfl_xor(v, d, 64);
    return v;
}

// async global->LDS, 16B per lane. Per-lane LDS dest follows uniform-base +
// lane*16 pattern exactly (c = j*BLK + tid), matching the HW requirement.
__device__ __forceinline__ void gload16(const float4* g, uint32_t* lds) {
    __builtin_amdgcn_global_load_lds(
        (const __attribute__((address_space(1))) uint32_t*)g,
        (__attribute__((address_space(3))) uint32_t*)lds,
        16, 0, 0);
}

__global__ void __launch_bounds__(BLK)
wta_kernel(const float* __restrict__ in, float* __restrict__ out, int nrows) {
    const int tid  = threadIdx.x;
    const int lane = tid & 63;
    const int wid  = tid >> 6;
    const int row0 = blockIdx.x * ROWS;
    if (row0 >= nrows) return;
    const int rcnt = (nrows - row0 < ROWS) ? (nrows - row0) : ROWS;

    __shared__ uint32_t buf[2][C4 * 4];      // 2 x 80000 B raw float bits
    __shared__ uint32_t candk[CAP];          // 3.5 KB candidate keys
    __shared__ uint32_t ctr[2][2];           // [parity][0]=cand count, [1]=hi count
    __shared__ uint32_t fcnt[2];             // fallback reduce slots
    __shared__ uint32_t bc[3];               // 0: T, 1: budget, 2: m
    __shared__ uint32_t waveTot[NW];

    const uint32_t KHI = 0x80000000u | __float_as_uint(T_HI_F);  // key of positive float
    const uint32_t KLO = 0x80000000u | __float_as_uint(T_LO_F);

    // ---- prologue: zero both counter parities, prefetch first row ----
    if (tid == 0) { ctr[0][0] = 0u; ctr[0][1] = 0u; ctr[1][0] = 0u; ctr[1][1] = 0u; }
    {
        const float4* g = (const float4*)(in + (size_t)row0 * D_DIM);
        #pragma unroll
        for (int j = 0; j < JPT; ++j) {
            int c = j * BLK + tid;
            if (c < C4) gload16(g + c, &buf[0][4 * c]);
        }
    }
    __syncthreads();                         // row 0 resident, counters zeroed

    int cur = 0;
    for (int i = 0; i < rcnt; ++i) {
        const int row = row0 + i;
        const int p   = i & 1;
        uint32_t* ctrC = ctr[p];
        uint32_t* ctrN = ctr[p ^ 1];

        // ---- scan LDS row: count > KHI, collect bracket candidates ----
        uint32_t cnt_hi = 0;
        #pragma unroll
        for (int j = 0; j < JPT; ++j) {
            int c = j * BLK + tid;
            if (c < C4) {
                uint4 w = *(const uint4*)&buf[cur][4 * c];
                uint32_t k0 = f2k(w.x), k1 = f2k(w.y), k2 = f2k(w.z), k3 = f2k(w.w);
                cnt_hi += (k0 > KHI) ? 1u : 0u;
                cnt_hi += (k1 > KHI) ? 1u : 0u;
                cnt_hi += (k2 > KHI) ? 1u : 0u;
                cnt_hi += (k3 > KHI) ? 1u : 0u;
                if (k0 > KLO && k0 <= KHI) { uint32_t q = atomicAdd(&ctrC[0], 1u); if (q < CAP) candk[q] = k0; }
                if (k1 > KLO && k1 <= KHI) { uint32_t q = atomicAdd(&ctrC[0], 1u); if (q < CAP) candk[q] = k1; }
                if (k2 > KLO && k2 <= KHI) { uint32_t q = atomicAdd(&ctrC[0], 1u); if (q < CAP) candk[q] = k2; }
                if (k3 > KLO && k3 <= KHI) { uint32_t q = atomicAdd(&ctrC[0], 1u); if (q < CAP) candk[q] = k3; }
            }
        }
        {
            uint32_t ws = wave_sum(cnt_hi);
            if (lane == 0) atomicAdd(&ctrC[1], ws);
        }
        if (tid == 0) { ctrN[0] = 0u; ctrN[1] = 0u; }   // zero next parity (no extra barrier)
        __syncthreads();                      // scan complete

        const uint32_t cm = ctrC[0];
        const uint32_t hi = ctrC[1];

        if (hi < K_SEL && K_SEL <= hi + cm && cm <= CAP) {
            // ---- exact select among bracket candidates (expected ~371) ----
            const uint32_t kp = K_SEL - hi;   // rank of target within candk
            for (uint32_t idx = (uint32_t)tid; idx < cm; idx += BLK) {
                uint32_t x = candk[idx];
                uint32_t gt = 0, eq = 0;
                uint32_t j = 0;
                for (; j + 8 <= cm; j += 8) {  // unrolled LDS broadcast reads
                    #pragma unroll
                    for (int u = 0; u < 8; ++u) {
                        uint32_t y = candk[j + u];
                        gt += (y > x) ? 1u : 0u;
                        eq += (y == x) ? 1u : 0u;
                    }
                }
                for (; j < cm; ++j) {
                    uint32_t y = candk[j];
                    gt += (y > x) ? 1u : 0u;
                    eq += (y == x) ? 1u : 0u;
                }
                if (gt < kp && kp <= gt + eq) {  // unique value-class wins
                    bc[0] = x;                   // T (kth-largest key)
                    bc[1] = kp - gt;             // budget among == T
                    bc[2] = eq;                  // m
                }
            }
        } else {
            // ---- exact fallback for any input: bitwise threshold search over
            // the LDS-resident row (correctness-only; ~never taken).
            uint32_t prefix = 0;
            for (int b = 31; b >= 0; --b) {
                uint32_t probe = prefix | (1u << b);
                uint32_t cc = 0;
                #pragma unroll
                for (int j = 0; j < JPT; ++j) {
                    int c = j * BLK + tid;
                    if (c < C4) {
                        uint4 w = *(const uint4*)&buf[cur][4 * c];
                        cc += (f2k(w.x) >= probe) ? 1u : 0u;
                        cc += (f2k(w.y) >= probe) ? 1u : 0u;
                        cc += (f2k(w.z) >= probe) ? 1u : 0u;
                        cc += (f2k(w.w) >= probe) ? 1u : 0u;
                    }
                }
                if (tid == 0) fcnt[0] = 0u;
                __syncthreads();
                uint32_t t = wave_sum(cc);
                if (lane == 0) atomicAdd(&fcnt[0], t);
                __syncthreads();
                if (fcnt[0] >= K_SEL) prefix = probe;
                __syncthreads();               // protect fcnt rezero next bit
            }
            uint32_t g = 0, q = 0;
            #pragma unroll
            for (int j = 0; j < JPT; ++j) {
                int c = j * BLK + tid;
                if (c < C4) {
                    uint4 w = *(const uint4*)&buf[cur][4 * c];
                    uint32_t kk[4] = { f2k(w.x), f2k(w.y), f2k(w.z), f2k(w.w) };
                    #pragma unroll
                    for (int u = 0; u < 4; ++u) {
                        g += (kk[u] >  prefix) ? 1u : 0u;
                        q += (kk[u] == prefix) ? 1u : 0u;
                    }
                }
            }
            if (tid == 0) { fcnt[0] = 0u; fcnt[1] = 0u; }
            __syncthreads();
            uint32_t tg = wave_sum(g);
            uint32_t tq = wave_sum(q);
            if (lane == 0) { atomicAdd(&fcnt[0], tg); atomicAdd(&fcnt[1], tq); }
            __syncthreads();
            if (tid == 0) { bc[0] = prefix; bc[1] = K_SEL - fcnt[0]; bc[2] = fcnt[1]; }
        }
        __syncthreads();                      // bc visible

        const uint32_t T      = bc[0];
        const uint32_t budget = bc[1];
        const uint32_t m      = bc[2];

        // ---- issue prefetch of next row NOW: streams under the output stores ----
        if (i + 1 < rcnt) {
            const float4* g = (const float4*)(in + (size_t)(row + 1) * D_DIM);
            #pragma unroll
            for (int j = 0; j < JPT; ++j) {
                int c = j * BLK + tid;
                if (c < C4) gload16(g + c, &buf[cur ^ 1][4 * c]);
            }
        }

        // ---- output from LDS ----
        vf4* out4 = (vf4*)(out + (size_t)row * D_DIM);
        if (m == budget) {
            // fast path: keep everything >= T (bit-exact pass-through)
            #pragma unroll
            for (int j = 0; j < JPT; ++j) {
                int c = j * BLK + tid;
                if (c < C4) {
                    uint4 w = *(const uint4*)&buf[cur][4 * c];
                    vf4 o;
                    o.x = (f2k(w.x) >= T) ? __uint_as_float(w.x) : 0.0f;
                    o.y = (f2k(w.y) >= T) ? __uint_as_float(w.y) : 0.0f;
                    o.z = (f2k(w.z) >= T) ? __uint_as_float(w.z) : 0.0f;
                    o.w = (f2k(w.w) >= T) ? __uint_as_float(w.w) : 0.0f;
                    __builtin_nontemporal_store(o, &out4[c]);
                }
            }
        } else {
            // rare tie path: among keys == T keep only the `budget` smallest
            // column indices (matches jax.lax.top_k stable tie-break). Chunk
            // order == (j, tid) order == increasing column, so an ordered
            // block scan gives exact ranks. (Barriers here also drain the
            // prefetch — harmless on this cold path.)
            uint32_t running = 0;
            #pragma unroll
            for (int j = 0; j < JPT; ++j) {
                int c = j * BLK + tid;
                bool valid = (c < C4);
                uint32_t b0 = 0u, b1 = 0u, b2 = 0u, b3 = 0u;
                if (valid) {
                    uint4 w = *(const uint4*)&buf[cur][4 * c];
                    b0 = w.x; b1 = w.y; b2 = w.z; b3 = w.w;
                }
                uint32_t k0 = f2k(b0), k1 = f2k(b1), k2 = f2k(b2), k3 = f2k(b3);
                uint32_t f0 = (valid && k0 == T) ? 1u : 0u;
                uint32_t f1 = (valid && k1 == T) ? 1u : 0u;
                uint32_t f2 = (valid && k2 == T) ? 1u : 0u;
                uint32_t f3 = (valid && k3 == T) ? 1u : 0u;
                uint32_t cnt = f0 + f1 + f2 + f3;

                uint32_t inc = cnt;
                #pragma unroll
                for (int d = 1; d < 64; d <<= 1) {
                    uint32_t v = __shfl_up(inc, d, 64);
                    if (lane >= d) inc += v;
                }
                if (lane == 63) waveTot[wid] = inc;
                __syncthreads();
                uint32_t waveBefore = 0, blockTot = 0;
                #pragma unroll
                for (int w = 0; w < NW; ++w) {
                    uint32_t t = waveTot[w];
                    blockTot += t;
                    if (w < wid) waveBefore += t;
                }
                uint32_t base = running + waveBefore + (inc - cnt);
                uint32_t r0 = base;
                uint32_t r1 = base + f0;
                uint32_t r2 = base + f0 + f1;
                uint32_t r3 = base + f0 + f1 + f2;
                if (valid) {
                    float4 o;
                    o.x = (k0 > T || (f0 && r0 < budget)) ? __uint_as_float(b0) : 0.0f;
                    o.y = (k1 > T || (f1 && r1 < budget)) ? __uint_as_float(b1) : 0.0f;
                    o.z = (k2 > T || (f2 && r2 < budget)) ? __uint_as_float(b2) : 0.0f;
                    o.w = (k3 > T || (f3 && r3 < budget)) ? __uint_as_float(b3) : 0.0f;
                    ((float4*)out4)[c] = o;
                }
                running += blockTot;
                __syncthreads();               // waveTot reuse next j
            }
        }

        __syncthreads();   // end of iter: drains prefetch + output stores;
                           // protects buf swap / candk / bc reuse
        cur ^= 1;
    }
}

extern "C" void kernel_launch(void* const* d_in, const int* in_sizes, int n_in,
                              void* d_out, int out_size, void* d_ws, size_t ws_size,
                              hipStream_t stream) {
    const float* in  = (const float*)d_in[0];
    float*       out = (float*)d_out;
    const int B = in_sizes[0] / D_DIM;         // 4096 rows
    const int nblk = (B + ROWS - 1) / ROWS;    // 256 blocks -> 1 per CU
    wta_kernel<<<dim3(nblk), dim3(BLK), 0, stream>>>(in, out, B);
}